// Round 20
// baseline (202.777 us; speedup 1.0000x reference)
//
#include <hip/hip_runtime.h>

#define DD 32
#define EPSF 1e-16f
#define BSH 5                    // 32 nodes per bucket
#define BNODES (1 << BSH)
#define BMAX 2048                // max buckets (N <= 65536)
#define CAP 2048                 // fixed pair capacity per bucket (32 sigma margin)
#define K3_TPB 512
#define K3_EPT 16
#define K3_EPB (K3_TPB * K3_EPT) // 8192 edges per binning block
#define CHUNK 1536               // pairs per aggregate LDS chunk
#define CPT (CHUNK / 256)        // 6 pairs per thread per chunk
// NOTE: eid packed into 21 bits -> requires E < 2^21. E = 1.6M ok.

typedef float vf4 __attribute__((ext_vector_type(4)));

// non-temporal float4 load (stream-once data; keep L2/L3 for reused buffers)
__device__ __forceinline__ vf4 ntload4(const float* p) {
    return __builtin_nontemporal_load(reinterpret_cast<const vf4*>(p));
}

// ---- K0: per-edge score, pure streaming (2 edges/thread); block 0 zeroes gcnt ----
__global__ void score_kernel(const float* __restrict__ ax,
                             const float* __restrict__ Wsf,
                             const float* __restrict__ bsf,
                             float* __restrict__ ex,
                             int* __restrict__ gcnt, int E, int B) {
    if (blockIdx.x == 0) {
        for (int b = threadIdx.x; b < B; b += blockDim.x) gcnt[b] = 0;
    }
    int i = blockIdx.x * blockDim.x + threadIdx.x;
    int e0 = i * 2;
    if (e0 >= E) return;
    bool two = (e0 + 1 < E);
    int e1 = two ? e0 + 1 : e0;

    const float* r0 = ax + (size_t)e0 * DD;
    const float* r1 = ax + (size_t)e1 * DD;
    float b = bsf[0];
    float s0 = b, s1 = b;
#pragma unroll
    for (int q = 0; q < 8; ++q) {
        vf4 f0 = ntload4(r0 + 4 * q);
        vf4 f1 = ntload4(r1 + 4 * q);
        float w0 = Wsf[4 * q], w1 = Wsf[4 * q + 1];
        float w2 = Wsf[4 * q + 2], w3 = Wsf[4 * q + 3];
        s0 = fmaf(f0[0], w0, s0); s0 = fmaf(f0[1], w1, s0);
        s0 = fmaf(f0[2], w2, s0); s0 = fmaf(f0[3], w3, s0);
        s1 = fmaf(f1[0], w0, s1); s1 = fmaf(f1[1], w1, s1);
        s1 = fmaf(f1[2], w2, s1); s1 = fmaf(f1[3], w3, s1);
    }
    float ex0 = __expf(s0), ex1 = __expf(s1);
    if (two) reinterpret_cast<float2*>(ex)[i] = make_float2(ex0, ex1);
    else     ex[e0] = ex0;
}

// ---- K3: two-pass bin, pos-remember (1 LDS atomic per edge) ----
__launch_bounds__(K3_TPB)
__global__ void bin_kernel(const int* __restrict__ index,
                           const float* __restrict__ ex,
                           int* __restrict__ gcnt,
                           uint2* __restrict__ pairs, int E, int B) {
    __shared__ int lcnt[BMAX];
    __shared__ int lbase[BMAX];
    int t = threadIdx.x;
    int base = blockIdx.x * K3_EPB;
    int nE = min(K3_EPB, E - base);

    for (int b = t; b < B; b += K3_TPB) lcnt[b] = 0;
    __syncthreads();

    // pass 1: count, remembering each edge's position within (block,bucket)
    int idxv[K3_EPT];
    int posv[K3_EPT];
#pragma unroll
    for (int i = 0; i < K3_EPT; ++i) {
        int off = i * K3_TPB + t;
        idxv[i] = -1;
        if (off < nE) {
            idxv[i] = index[base + off];
            posv[i] = atomicAdd(&lcnt[idxv[i] >> BSH], 1);
        }
    }
    __syncthreads();

    // alloc chunk inside the bucket's fixed region.
    // each bucket b is touched by exactly one thread (b mod 512 == t).
    for (int b = t; b < B; b += K3_TPB) {
        int c = lcnt[b];
        lbase[b] = (c > 0) ? (b * CAP + atomicAdd(&gcnt[b], c)) : 0;
    }
    __syncthreads();

    // pass 2: place (token, ex) at remembered position — no atomic
#pragma unroll
    for (int i = 0; i < K3_EPT; ++i) {
        int off = i * K3_TPB + t;
        if (off >= nE) continue;
        int e = base + off;
        float exv = ex[e];
        int idx = idxv[i];
        int b = idx >> BSH;
        pairs[lbase[b] + posv[i]] =
            make_uint2((unsigned)e | ((unsigned)(idx & (BNODES - 1)) << 21),
                       __float_as_uint(exv));
    }
}

// ---- K4: block per bucket — pos-remember counting-sort, register gather ----
__launch_bounds__(256)
__global__ void aggregate_kernel(const float* __restrict__ x,
                                 const uint2* __restrict__ pairs,
                                 const int* __restrict__ gcnt,
                                 const float* __restrict__ Wf,   // [DD][DD]
                                 const float* __restrict__ bfv,  // [DD]
                                 float* __restrict__ out, int N) {
    __shared__ uint2 sp[CHUNK];            // node-sorted (token, ex) of chunk
    __shared__ int cnt[BNODES];
    __shared__ int offs[BNODES + 1];

    int bk = blockIdx.x;
    int nbase = bk << BSH;
    int t = threadIdx.x;
    int wid = t >> 6;
    int lane = t & 63;
    int half = lane >> 5;
    int k = lane & 31;

    int beg = bk * CAP;
    int end = beg + gcnt[bk];

    float yacc[8], dacc[8];
#pragma unroll
    for (int s = 0; s < 8; ++s) { yacc[s] = 0.0f; dacc[s] = 0.0f; }

    for (int cb = beg; cb < end; cb += CHUNK) {
        int csz = min(CHUNK, end - cb);

        // coalesced load of this chunk's pairs into registers
        uint2 vreg[CPT];
        int posv[CPT];
#pragma unroll
        for (int j = 0; j < CPT; ++j) {
            int i = j * 256 + t;
            vreg[j].x = 0xFFFFFFFFu;
            if (i < csz) vreg[j] = pairs[cb + i];
        }

        if (t < BNODES) cnt[t] = 0;
        __syncthreads();
        // count, remembering position within node segment
#pragma unroll
        for (int j = 0; j < CPT; ++j)
            if (vreg[j].x != 0xFFFFFFFFu)
                posv[j] = atomicAdd(&cnt[(vreg[j].x >> 21) & (BNODES - 1)], 1);
        __syncthreads();
        // wave-parallel exclusive scan over the 32 bins (wave 0)
        if (t < 32) {
            int c = cnt[t];
            int v = c;
#pragma unroll
            for (int d = 1; d < 32; d <<= 1) {
                int u = __shfl_up(v, d, 32);
                if (t >= d) v += u;
            }
            offs[t] = v - c;
            if (t == 31) offs[BNODES] = v;
        }
        __syncthreads();
        // place at remembered position — no atomic
#pragma unroll
        for (int j = 0; j < CPT; ++j) {
            if (vreg[j].x != 0xFFFFFFFFu) {
                int nl = (vreg[j].x >> 21) & (BNODES - 1);
                sp[offs[nl] + posv[j]] = vreg[j];
            }
        }
        __syncthreads();

        // register gather: wave wid owns nodes wid*8 .. wid*8+7
        // up to 16 x-rows in flight per half-wave (32 per wave); nt loads
#pragma unroll
        for (int s = 0; s < 8; ++s) {
            int nl = wid * 8 + s;
            int lo = offs[nl], hi = offs[nl + 1];
            float ya = 0.0f, da = 0.0f;
            int p = lo + half;
            for (; p + 30 < hi; p += 32) {
                uint2 a[16];
                float w[16], xv[16];
#pragma unroll
                for (int u = 0; u < 16; ++u) a[u] = sp[p + 2 * u];
#pragma unroll
                for (int u = 0; u < 16; ++u) {
                    w[u] = __uint_as_float(a[u].y);
                    xv[u] = __builtin_nontemporal_load(
                        x + (size_t)(a[u].x & 0x1FFFFFu) * DD + k);
                }
#pragma unroll
                for (int u = 0; u < 16; ++u) {
                    ya = fmaf(w[u], xv[u], ya);
                    da += w[u];
                }
            }
            for (; p + 6 < hi; p += 8) {
                uint2 a0 = sp[p],     a1 = sp[p + 2];
                uint2 a2 = sp[p + 4], a3 = sp[p + 6];
                float w0 = __uint_as_float(a0.y), w1 = __uint_as_float(a1.y);
                float w2 = __uint_as_float(a2.y), w3 = __uint_as_float(a3.y);
                float x0 = __builtin_nontemporal_load(
                    x + (size_t)(a0.x & 0x1FFFFFu) * DD + k);
                float x1 = __builtin_nontemporal_load(
                    x + (size_t)(a1.x & 0x1FFFFFu) * DD + k);
                float x2 = __builtin_nontemporal_load(
                    x + (size_t)(a2.x & 0x1FFFFFu) * DD + k);
                float x3 = __builtin_nontemporal_load(
                    x + (size_t)(a3.x & 0x1FFFFFu) * DD + k);
                ya = fmaf(w0, x0, ya); ya = fmaf(w1, x1, ya);
                ya = fmaf(w2, x2, ya); ya = fmaf(w3, x3, ya);
                da += (w0 + w1) + (w2 + w3);
            }
            for (; p < hi; p += 2) {
                uint2 a = sp[p];
                float w = __uint_as_float(a.y);
                float xv = __builtin_nontemporal_load(
                    x + (size_t)(a.x & 0x1FFFFFu) * DD + k);
                ya = fmaf(w, xv, ya);
                da += w;
            }
            yacc[s] += ya;
            dacc[s] += da;
        }
        __syncthreads();  // sp reused next chunk
    }

    // epilogue: combine halves, normalize, apply W, write
#pragma unroll
    for (int s = 0; s < 8; ++s) {
        float ya = yacc[s] + __shfl_xor(yacc[s], 32);
        float da = dacc[s] + __shfl_xor(dacc[s], 32);
        int node = nbase + wid * 8 + s;
        if (node < N) {
            float inv = 1.0f / (da + EPSF);
            float yn = ya * inv;
            float sw = da * inv;
            float o = sw * bfv[k];
#pragma unroll
            for (int kk = 0; kk < DD; ++kk)
                o = fmaf(__shfl(yn, kk), Wf[kk * DD + k], o);
            if (half == 0) out[(size_t)node * DD + k] = o;
        }
    }
}

extern "C" void kernel_launch(void* const* d_in, const int* in_sizes, int n_in,
                              void* d_out, int out_size, void* d_ws, size_t ws_size,
                              hipStream_t stream) {
    const float* x       = (const float*)d_in[0];
    const float* ax      = (const float*)d_in[1];
    const int*   index   = (const int*)d_in[2];
    // d_in[3] = size scalar; N derived from out_size
    const float* W_emb   = (const float*)d_in[4];
    const float* b_emb   = (const float*)d_in[5];
    const float* W_score = (const float*)d_in[6];
    const float* b_score = (const float*)d_in[7];

    int E = in_sizes[0] / DD;
    int N = out_size / DD;
    int B = (N + BNODES - 1) >> BSH;   // 1563 for N=50000 (<= BMAX)

    // workspace: pairs[B*CAP] 25.6 MB + ex[E] 6.4 MB + gcnt[B] (ws ~800 MB)
    uint2* pairs = (uint2*)d_ws;                      // [B*CAP]
    float* ex    = (float*)(pairs + (size_t)B * CAP); // [E]
    int*   gcnt  = (int*)(ex + (size_t)E);            // [B]

    int blocksE2 = ((E + 1) / 2 + 255) / 256;
    score_kernel<<<blocksE2, 256, 0, stream>>>(ax, W_score, b_score, ex,
                                               gcnt, E, B);

    int blocksK = (E + K3_EPB - 1) / K3_EPB;
    bin_kernel<<<blocksK, K3_TPB, 0, stream>>>(index, ex, gcnt, pairs, E, B);
    aggregate_kernel<<<B, 256, 0, stream>>>(x, pairs, gcnt, W_emb, b_emb,
                                            (float*)d_out, N);
}

// Round 21
// 148.901 us; speedup vs baseline: 1.3618x; 1.3618x over previous
//
#include <hip/hip_runtime.h>

#define DD 32
#define EPSF 1e-16f
#define BSH 5                    // 32 nodes per bucket
#define BNODES (1 << BSH)
#define BMAX 2048                // max buckets (N <= 65536)
#define CAP 2048                 // fixed pair capacity per bucket (32 sigma margin)
#define K3_TPB 512
#define K3_EPT 16
#define K3_EPB (K3_TPB * K3_EPT) // 8192 edges per binning block
#define CHUNK 1536               // pairs per aggregate LDS chunk
#define CPT (CHUNK / 256)        // 6 pairs per thread per chunk
// NOTE: eid packed into 21 bits -> requires E < 2^21. E = 1.6M ok.

// ---- K0: per-edge score, pure streaming (2 edges/thread); block 0 zeroes gcnt ----
__global__ void score_kernel(const float* __restrict__ ax,
                             const float* __restrict__ Wsf,
                             const float* __restrict__ bsf,
                             float* __restrict__ ex,
                             int* __restrict__ gcnt, int E, int B) {
    if (blockIdx.x == 0) {
        for (int b = threadIdx.x; b < B; b += blockDim.x) gcnt[b] = 0;
    }
    int i = blockIdx.x * blockDim.x + threadIdx.x;
    int e0 = i * 2;
    if (e0 >= E) return;
    bool two = (e0 + 1 < E);
    int e1 = two ? e0 + 1 : e0;

    const float4* r0 = reinterpret_cast<const float4*>(ax + (size_t)e0 * DD);
    const float4* r1 = reinterpret_cast<const float4*>(ax + (size_t)e1 * DD);
    float b = bsf[0];
    float s0 = b, s1 = b;
#pragma unroll
    for (int q = 0; q < 8; ++q) {
        float4 f0 = r0[q];
        float4 f1 = r1[q];
        float w0 = Wsf[4 * q], w1 = Wsf[4 * q + 1];
        float w2 = Wsf[4 * q + 2], w3 = Wsf[4 * q + 3];
        s0 = fmaf(f0.x, w0, s0); s0 = fmaf(f0.y, w1, s0);
        s0 = fmaf(f0.z, w2, s0); s0 = fmaf(f0.w, w3, s0);
        s1 = fmaf(f1.x, w0, s1); s1 = fmaf(f1.y, w1, s1);
        s1 = fmaf(f1.z, w2, s1); s1 = fmaf(f1.w, w3, s1);
    }
    float ex0 = __expf(s0), ex1 = __expf(s1);
    if (two) reinterpret_cast<float2*>(ex)[i] = make_float2(ex0, ex1);
    else     ex[e0] = ex0;
}

// ---- K3: two-pass bin, pos-remember (1 LDS atomic per edge) ----
__launch_bounds__(K3_TPB)
__global__ void bin_kernel(const int* __restrict__ index,
                           const float* __restrict__ ex,
                           int* __restrict__ gcnt,
                           uint2* __restrict__ pairs, int E, int B) {
    __shared__ int lcnt[BMAX];
    __shared__ int lbase[BMAX];
    int t = threadIdx.x;
    int base = blockIdx.x * K3_EPB;
    int nE = min(K3_EPB, E - base);

    for (int b = t; b < B; b += K3_TPB) lcnt[b] = 0;
    __syncthreads();

    // pass 1: count, remembering each edge's position within (block,bucket)
    int idxv[K3_EPT];
    int posv[K3_EPT];
#pragma unroll
    for (int i = 0; i < K3_EPT; ++i) {
        int off = i * K3_TPB + t;
        idxv[i] = -1;
        if (off < nE) {
            idxv[i] = index[base + off];
            posv[i] = atomicAdd(&lcnt[idxv[i] >> BSH], 1);
        }
    }
    __syncthreads();

    // alloc chunk inside the bucket's fixed region.
    // each bucket b is touched by exactly one thread (b mod 512 == t).
    for (int b = t; b < B; b += K3_TPB) {
        int c = lcnt[b];
        lbase[b] = (c > 0) ? (b * CAP + atomicAdd(&gcnt[b], c)) : 0;
    }
    __syncthreads();

    // pass 2: place (token, ex) at remembered position — no atomic
#pragma unroll
    for (int i = 0; i < K3_EPT; ++i) {
        int off = i * K3_TPB + t;
        if (off >= nE) continue;
        int e = base + off;
        float exv = ex[e];
        int idx = idxv[i];
        int b = idx >> BSH;
        pairs[lbase[b] + posv[i]] =
            make_uint2((unsigned)e | ((unsigned)(idx & (BNODES - 1)) << 21),
                       __float_as_uint(exv));
    }
}

// ---- K4: block per bucket — pos-remember counting-sort, register gather ----
__launch_bounds__(256)
__global__ void aggregate_kernel(const float* __restrict__ x,
                                 const uint2* __restrict__ pairs,
                                 const int* __restrict__ gcnt,
                                 const float* __restrict__ Wf,   // [DD][DD]
                                 const float* __restrict__ bfv,  // [DD]
                                 float* __restrict__ out, int N) {
    __shared__ uint2 sp[CHUNK];            // node-sorted (token, ex) of chunk
    __shared__ int cnt[BNODES];
    __shared__ int offs[BNODES + 1];

    int bk = blockIdx.x;
    int nbase = bk << BSH;
    int t = threadIdx.x;
    int wid = t >> 6;
    int lane = t & 63;
    int half = lane >> 5;
    int k = lane & 31;

    int beg = bk * CAP;
    int end = beg + gcnt[bk];

    float yacc[8], dacc[8];
#pragma unroll
    for (int s = 0; s < 8; ++s) { yacc[s] = 0.0f; dacc[s] = 0.0f; }

    for (int cb = beg; cb < end; cb += CHUNK) {
        int csz = min(CHUNK, end - cb);

        // coalesced load of this chunk's pairs into registers
        uint2 vreg[CPT];
        int posv[CPT];
#pragma unroll
        for (int j = 0; j < CPT; ++j) {
            int i = j * 256 + t;
            vreg[j].x = 0xFFFFFFFFu;
            if (i < csz) vreg[j] = pairs[cb + i];
        }

        if (t < BNODES) cnt[t] = 0;
        __syncthreads();
        // count, remembering position within node segment
#pragma unroll
        for (int j = 0; j < CPT; ++j)
            if (vreg[j].x != 0xFFFFFFFFu)
                posv[j] = atomicAdd(&cnt[(vreg[j].x >> 21) & (BNODES - 1)], 1);
        __syncthreads();
        // wave-parallel exclusive scan over the 32 bins (wave 0)
        if (t < 32) {
            int c = cnt[t];
            int v = c;
#pragma unroll
            for (int d = 1; d < 32; d <<= 1) {
                int u = __shfl_up(v, d, 32);
                if (t >= d) v += u;
            }
            offs[t] = v - c;
            if (t == 31) offs[BNODES] = v;
        }
        __syncthreads();
        // place at remembered position — no atomic
#pragma unroll
        for (int j = 0; j < CPT; ++j) {
            if (vreg[j].x != 0xFFFFFFFFu) {
                int nl = (vreg[j].x >> 21) & (BNODES - 1);
                sp[offs[nl] + posv[j]] = vreg[j];
            }
        }
        __syncthreads();

        // register gather: wave wid owns nodes wid*8 .. wid*8+7
        // up to 16 x-rows in flight per half-wave (32 per wave)
#pragma unroll
        for (int s = 0; s < 8; ++s) {
            int nl = wid * 8 + s;
            int lo = offs[nl], hi = offs[nl + 1];
            float ya = 0.0f, da = 0.0f;
            int p = lo + half;
            for (; p + 30 < hi; p += 32) {
                uint2 a[16];
                float w[16], xv[16];
#pragma unroll
                for (int u = 0; u < 16; ++u) a[u] = sp[p + 2 * u];
#pragma unroll
                for (int u = 0; u < 16; ++u) {
                    w[u] = __uint_as_float(a[u].y);
                    xv[u] = x[(size_t)(a[u].x & 0x1FFFFFu) * DD + k];
                }
#pragma unroll
                for (int u = 0; u < 16; ++u) {
                    ya = fmaf(w[u], xv[u], ya);
                    da += w[u];
                }
            }
            for (; p + 6 < hi; p += 8) {
                uint2 a0 = sp[p],     a1 = sp[p + 2];
                uint2 a2 = sp[p + 4], a3 = sp[p + 6];
                float w0 = __uint_as_float(a0.y), w1 = __uint_as_float(a1.y);
                float w2 = __uint_as_float(a2.y), w3 = __uint_as_float(a3.y);
                float x0 = x[(size_t)(a0.x & 0x1FFFFFu) * DD + k];
                float x1 = x[(size_t)(a1.x & 0x1FFFFFu) * DD + k];
                float x2 = x[(size_t)(a2.x & 0x1FFFFFu) * DD + k];
                float x3 = x[(size_t)(a3.x & 0x1FFFFFu) * DD + k];
                ya = fmaf(w0, x0, ya); ya = fmaf(w1, x1, ya);
                ya = fmaf(w2, x2, ya); ya = fmaf(w3, x3, ya);
                da += (w0 + w1) + (w2 + w3);
            }
            for (; p < hi; p += 2) {
                uint2 a = sp[p];
                float w = __uint_as_float(a.y);
                ya = fmaf(w, x[(size_t)(a.x & 0x1FFFFFu) * DD + k], ya);
                da += w;
            }
            yacc[s] += ya;
            dacc[s] += da;
        }
        __syncthreads();  // sp reused next chunk
    }

    // epilogue: combine halves, normalize, apply W, write
#pragma unroll
    for (int s = 0; s < 8; ++s) {
        float ya = yacc[s] + __shfl_xor(yacc[s], 32);
        float da = dacc[s] + __shfl_xor(dacc[s], 32);
        int node = nbase + wid * 8 + s;
        if (node < N) {
            float inv = 1.0f / (da + EPSF);
            float yn = ya * inv;
            float sw = da * inv;
            float o = sw * bfv[k];
#pragma unroll
            for (int kk = 0; kk < DD; ++kk)
                o = fmaf(__shfl(yn, kk), Wf[kk * DD + k], o);
            if (half == 0) out[(size_t)node * DD + k] = o;
        }
    }
}

extern "C" void kernel_launch(void* const* d_in, const int* in_sizes, int n_in,
                              void* d_out, int out_size, void* d_ws, size_t ws_size,
                              hipStream_t stream) {
    const float* x       = (const float*)d_in[0];
    const float* ax      = (const float*)d_in[1];
    const int*   index   = (const int*)d_in[2];
    // d_in[3] = size scalar; N derived from out_size
    const float* W_emb   = (const float*)d_in[4];
    const float* b_emb   = (const float*)d_in[5];
    const float* W_score = (const float*)d_in[6];
    const float* b_score = (const float*)d_in[7];

    int E = in_sizes[0] / DD;
    int N = out_size / DD;
    int B = (N + BNODES - 1) >> BSH;   // 1563 for N=50000 (<= BMAX)

    // workspace: pairs[B*CAP] 25.6 MB + ex[E] 6.4 MB + gcnt[B] (ws ~800 MB)
    uint2* pairs = (uint2*)d_ws;                      // [B*CAP]
    float* ex    = (float*)(pairs + (size_t)B * CAP); // [E]
    int*   gcnt  = (int*)(ex + (size_t)E);            // [B]

    int blocksE2 = ((E + 1) / 2 + 255) / 256;
    score_kernel<<<blocksE2, 256, 0, stream>>>(ax, W_score, b_score, ex,
                                               gcnt, E, B);

    int blocksK = (E + K3_EPB - 1) / K3_EPB;
    bin_kernel<<<blocksK, K3_TPB, 0, stream>>>(index, ex, gcnt, pairs, E, B);
    aggregate_kernel<<<B, 256, 0, stream>>>(x, pairs, gcnt, W_emb, b_emb,
                                            (float*)d_out, N);
}